// Round 9
// baseline (145.021 us; speedup 1.0000x reference)
//
#include <hip/hip_runtime.h>
#include <hip/hip_bf16.h>

#define BLK 256
#define WPB 4                      // waves per block
#define TB 4                       // template B-frags resident per wave (128 cols/block)
#define TSPLITS 54                 // 54*128 = 6912 padded template columns
#define SGROUPS 18                 // 18*4 waves = 72 ssplits
#define SA 22                      // scan A-frags per wave; 72*22 = 1584 frags (exact)
#define COLS (TSPLITS * TB * 32)   // 6912
#define NBLOCKS (TSPLITS * SGROUPS)// 972
#define CTR_OFF 524288             // ctr at ws+512KB (partials use 486KB)
#define THRESH 0.1f
#define KEY_MAX 0xFFFFFFFFu
#define ONE2 0x3F803F80u           // bf16(1.0) | bf16(1.0)<<16

typedef __attribute__((ext_vector_type(8))) short short8;
typedef __attribute__((ext_vector_type(16))) float floatx16;

// bf16 round-to-nearest-even helpers
__device__ __forceinline__ unsigned short f2bf(float x) {
    unsigned u = __float_as_uint(x);
    unsigned r = u + 0x7FFFu + ((u >> 16) & 1u);
    return (unsigned short)(r >> 16);
}
__device__ __forceinline__ float bf2f(unsigned short h) {
    return __uint_as_float(((unsigned)h) << 16);
}
// split-pack: word = bf16_hi(v) | bf16_lo(residual) << 16
__device__ __forceinline__ unsigned packsplit(float v) {
    const unsigned short h = f2bf(v);
    const unsigned short l = f2bf(v - bf2f(h));
    return (unsigned)h | ((unsigned)l << 16);
}

// Order-preserving float->uint map: min in key space == min in float space.
__device__ __forceinline__ unsigned f2key(float f) {
    unsigned b = __float_as_uint(f);
    return (b & 0x80000000u) ? ~b : (b | 0x80000000u);
}
__device__ __forceinline__ float key2f(unsigned k) {
    return __uint_as_float((k & 0x80000000u) ? (k & 0x7FFFFFFFu) : ~k);
}

// Template B-frag word pattern (identical to R3-R8):
//   lanes 0-31 (lo):  {xh|xh, xl|xl, yh|yh, yl|yl}
//   lanes 32-63 (hi): {zh|zh, zl|zl, wh|wl, ONE2}   (w = t2, packed h|l)
__device__ __forceinline__ uint4 build_tmpl_frag(const float* __restrict__ tmpl,
                                                 int c, bool hi) {
    const float x = tmpl[3 * c + 0], y = tmpl[3 * c + 1], z = tmpl[3 * c + 2];
    const float t2 = fmaf(x, x, fmaf(y, y, z * z));
    const float a0 = hi ? z : x;
    const float a1 = hi ? t2 : y;
    const unsigned short h0 = f2bf(a0);
    const unsigned short l0 = f2bf(a0 - bf2f(h0));
    const unsigned short h1 = f2bf(a1);
    const unsigned short l1 = f2bf(a1 - bf2f(h1));
    uint4 u;
    u.x = (unsigned)h0 | ((unsigned)h0 << 16);
    u.y = (unsigned)l0 | ((unsigned)l0 << 16);
    u.z = hi ? ((unsigned)h1 | ((unsigned)l1 << 16))
             : ((unsigned)h1 | ((unsigned)h1 << 16));
    u.w = hi ? ONE2
             : ((unsigned)l1 | ((unsigned)l1 << 16));
    return u;
}

// min over the 16 scan rows of a d-tile (min3 tree) into the running min.
__device__ __forceinline__ float dtile_min(const floatx16 d, float mn) {
    const float t0 = fminf(fminf(d[0], d[1]), d[2]);
    const float t1 = fminf(fminf(d[3], d[4]), d[5]);
    const float t2 = fminf(fminf(d[6], d[7]), d[8]);
    const float t3 = fminf(fminf(d[9], d[10]), d[11]);
    const float t4 = fminf(fminf(d[12], d[13]), d[14]);
    const float u0 = fminf(fminf(t0, t1), t2);
    const float u1 = fminf(fminf(t3, t4), d[15]);
    return fminf(fminf(u0, u1), mn);
}

// R9. R8's REP probe measured the K-loop at 8.5us/pass marginal vs main's
// ~24us average -> sub-linear cost = clock-ramp signature (short kernel after
// a 40us memory-saturated fill runs at depressed DVFS clock; structural fixes
// R3-R7 were all null because none change the clock). Strategy: cut ABSOLUTE
// cycles + dispatches. (a) geometry (54,18), SA=22: same 97.6%-efficient tile
// cover, but waves 8640->3888 (halves wave-epilogue work, partials 40->18);
// (b) final kernel FUSED via ticket: all blocks fence + atomicAdd a
// memset-zeroed counter; ticket NBLOCKS-1 (all others provably done+fenced)
// reduces the 18 partials/col and writes out[0] directly (sole writer, no
// pre-zero, no atomic); saves one launch+gap. Live set ~96 VGPR @ cap 128.
__global__ __launch_bounds__(BLK, 4) void pdl_main(const float* __restrict__ scan,
                                                   const float* __restrict__ tmpl,
                                                   unsigned* __restrict__ partial,
                                                   unsigned* __restrict__ ctr,
                                                   float* __restrict__ out,
                                                   int N, int M) {
    const int tid = threadIdx.x;
    const int wave = tid >> 6, lane = tid & 63;
    const bool hi = (lane >= 32);
    const int tsplit = blockIdx.x;                 // 0..53: which 128 template cols
    const int sgroup = blockIdx.y;                 // 0..17
    const int ssplit = sgroup * WPB + wave;        // 0..71: which 22 scan frags

    __shared__ unsigned lmin[TB * 32];
    if (tid < TB * 32) lmin[tid] = KEY_MAX;

    union U { uint4 u; short8 s; };

    // Resident template B-frags (same for all 4 waves of the block).
    U B[TB];
    const int cbase = tsplit * (TB * 32) + (lane & 31);
#pragma unroll
    for (int j = 0; j < TB; ++j) {
        int c = cbase + j * 32;
        if (c > M - 1) c = M - 1;  // clamped dup col; finale ignores m>=M
        B[j].u = build_tmpl_frag(tmpl, c, hi);
    }

    float mn[TB];
#pragma unroll
    for (int j = 0; j < TB; ++j) mn[j] = 3e30f;

    floatx16 zacc;
#pragma unroll
    for (int r = 0; r < 16; ++r) zacc[r] = 0.0f;

    // Stream this wave's 22 scan A-frags; coords prefetched one frag ahead.
    // A-frag pattern (identical products to R3-R8; -2 folded in):
    //   lanes 0-31 (lo):  {P(-2x), P(-2x), P(-2y), P(-2y)}
    //   lanes 32-63 (hi): {P(-2z), P(-2z), ONE2,   P(s2) }
    const int nbase = ssplit * (SA * 32) + (lane & 31);
    int n0 = nbase; if (n0 > N - 1) n0 = N - 1;    // clamp: dup row, min-idempotent
    float x = scan[3 * n0 + 0], y = scan[3 * n0 + 1], z = scan[3 * n0 + 2];
#pragma unroll 1
    for (int f = 0; f < SA; ++f) {
        int n1 = nbase + (f + 1) * 32; if (n1 > N - 1) n1 = N - 1;  // last iter: dup
        const float nx = scan[3 * n1 + 0];
        const float ny = scan[3 * n1 + 1];
        const float nz = scan[3 * n1 + 2];
        const float s2 = fmaf(x, x, fmaf(y, y, z * z));
        const float c0 = -2.0f * (hi ? z : x);
        const float c1 = hi ? s2 : (-2.0f * y);
        U a;
        a.u.x = packsplit(c0);
        a.u.y = a.u.x;
        a.u.z = hi ? ONE2 : packsplit(c1);
        a.u.w = hi ? packsplit(c1) : a.u.z;
        {
            const floatx16 d0 =
                __builtin_amdgcn_mfma_f32_32x32x16_bf16(a.s, B[0].s, zacc, 0, 0, 0);
            const floatx16 d1 =
                __builtin_amdgcn_mfma_f32_32x32x16_bf16(a.s, B[1].s, zacc, 0, 0, 0);
            mn[0] = dtile_min(d0, mn[0]);
            mn[1] = dtile_min(d1, mn[1]);
        }
        {
            const floatx16 d0 =
                __builtin_amdgcn_mfma_f32_32x32x16_bf16(a.s, B[2].s, zacc, 0, 0, 0);
            const floatx16 d1 =
                __builtin_amdgcn_mfma_f32_32x32x16_bf16(a.s, B[3].s, zacc, 0, 0, 0);
            mn[2] = dtile_min(d0, mn[2]);
            mn[3] = dtile_min(d1, mn[3]);
        }
        x = nx; y = ny; z = nz;
    }

    __syncthreads();  // lmin init complete before any atomics

    // Merge complementary row-halves (lane ^ 32 holds the other 16 scan rows
    // of the same template column), then block-level LDS merge.
#pragma unroll
    for (int j = 0; j < TB; ++j) {
        const float o = __shfl_xor(mn[j], 32, 64);
        const float v = fminf(mn[j], o);
        if (lane < 32) atomicMin(&lmin[j * 32 + lane], f2key(v));
    }
    __syncthreads();

    // Private (non-atomic) partial slot: no init needed on poisoned ws.
    const size_t base = (size_t)sgroup * COLS + (size_t)tsplit * (TB * 32);
    if (tid < TB * 32) partial[base + tid] = lmin[tid];

    // ---- Ticket: last block to finish runs the finale. All threads fence
    // (own partial stores globally visible), then one device-scope atomicAdd.
    __threadfence();
    __syncthreads();
    __shared__ unsigned tkt;
    if (tid == 0) tkt = atomicAdd(ctr, 1u);
    __syncthreads();
    if (tkt != NBLOCKS - 1) return;

    // Finale (sole block; 971 prior fenced increments -> all partials visible).
    __threadfence();
    float s = 0.0f;
#pragma unroll 1
    for (int c = 0; c < COLS / BLK; ++c) {         // 27 column-chunks
        const int m = c * BLK + tid;
        unsigned k = partial[m];                   // g = 0
#pragma unroll
        for (int g = 1; g < SGROUPS; ++g)
            k = min(k, partial[(size_t)g * COLS + m]);
        const float v = key2f(k);
        if (m < M && v < THRESH) s += v;
    }
#pragma unroll
    for (int off = 32; off > 0; off >>= 1) s += __shfl_down(s, off, 64);

    __shared__ float ls[BLK / 64];
    if (lane == 0) ls[wave] = s;
    __syncthreads();
    if (tid == 0) {
        float t = 0.0f;
#pragma unroll
        for (int i = 0; i < BLK / 64; ++i) t += ls[i];
        out[0] = t;  // sole writer: no pre-zero, no atomic
    }
}

extern "C" void kernel_launch(void* const* d_in, const int* in_sizes, int n_in,
                              void* d_out, int out_size, void* d_ws, size_t ws_size,
                              hipStream_t stream) {
    const float* scan = (const float*)d_in[0];   // [N,3] fp32
    const float* tmpl = (const float*)d_in[1];   // [M,3] fp32
    float* out = (float*)d_out;                  // scalar fp32

    const int N = in_sizes[0] / 3;               // 50000
    const int M = in_sizes[1] / 3;               // 6890

    // ws: partial[SGROUPS][COLS] (486 KB) at 0; ticket counter at +512KB.
    unsigned* partial = (unsigned*)d_ws;
    unsigned* ctr = (unsigned*)((char*)d_ws + CTR_OFF);

    hipMemsetAsync(ctr, 0, 4, stream);           // stream-ordered, capture-safe

    dim3 grid(TSPLITS, SGROUPS);                 // (54, 18) = 972 blocks
    pdl_main<<<grid, BLK, 0, stream>>>(scan, tmpl, partial, ctr, out, N, M);
}

// Round 11
// 72.879 us; speedup vs baseline: 1.9899x; 1.9899x over previous
//
#include <hip/hip_runtime.h>
#include <hip/hip_bf16.h>

#define BLK 256
#define WPB 4                      // waves per block
#define TB 4                       // template B-frags resident per wave (128 cols/block)
#define TSPLITS 54                 // 54*128 = 6912 padded template columns
#define SA 10                      // scan A-frags per wave (fully unrolled)
#define SGROUPS 40                 // blockIdx.y; 40*4 waves = 160 ssplits (covers 51200)
#define COLS (TSPLITS * TB * 32)   // 6912
#define THRESH 0.1f
#define KEY_MAX 0xFFFFFFFFu
#define ONE2 0x3F803F80u           // bf16(1.0) | bf16(1.0)<<16

typedef __attribute__((ext_vector_type(8))) short short8;
typedef __attribute__((ext_vector_type(16))) float floatx16;

// bf16 round-to-nearest-even helpers
__device__ __forceinline__ unsigned short f2bf(float x) {
    unsigned u = __float_as_uint(x);
    unsigned r = u + 0x7FFFu + ((u >> 16) & 1u);
    return (unsigned short)(r >> 16);
}
__device__ __forceinline__ float bf2f(unsigned short h) {
    return __uint_as_float(((unsigned)h) << 16);
}
// split-pack: word = bf16_hi(v) | bf16_lo(residual) << 16
__device__ __forceinline__ unsigned packsplit(float v) {
    const unsigned short h = f2bf(v);
    const unsigned short l = f2bf(v - bf2f(h));
    return (unsigned)h | ((unsigned)l << 16);
}

// Order-preserving float->uint map: min in key space == min in float space.
__device__ __forceinline__ unsigned f2key(float f) {
    unsigned b = __float_as_uint(f);
    return (b & 0x80000000u) ? ~b : (b | 0x80000000u);
}
__device__ __forceinline__ float key2f(unsigned k) {
    return __uint_as_float((k & 0x80000000u) ? (k & 0x7FFFFFFFu) : ~k);
}

// min over the 16 scan rows of a d-tile (min3 tree) into the running min.
__device__ __forceinline__ float dtile_min(const floatx16 d, float mn) {
    const float t0 = fminf(fminf(d[0], d[1]), d[2]);
    const float t1 = fminf(fminf(d[3], d[4]), d[5]);
    const float t2 = fminf(fminf(d[6], d[7]), d[8]);
    const float t3 = fminf(fminf(d[9], d[10]), d[11]);
    const float t4 = fminf(fminf(d[12], d[13]), d[14]);
    const float u0 = fminf(fminf(t0, t1), t2);
    const float u1 = fminf(fminf(t3, t4), d[15]);
    return fminf(fminf(u0, u1), mn);
}

// R11 = R10 resubmitted verbatim (R10's bench was an infrastructure failure:
// "MI355X container failed twice"; the kernel never ran). R10 = revert to R7
// best-family (73.3us; zero-memory inner loop, (54,40), 8640 waves, separate
// tiny final). R9's two changes both regressed (waves halved -> less TLP
// during the DVFS ramp; ticket finale -> ~0-occupancy tail + codegen
// perturbation to VGPR=36). One polish kept: ALL cold-prologue loads
// (30 scan + 12 tmpl dwords, HBM-cold after the poison fill) are issued
// before any dependent pack math.
// Ledger for the roofline case: fill=40us @84% HBM (harness); steady-state
// full-cover pass = 8.5us (R8 marginal, = MFMA+min3 issue floor at ramped
// clock); effective clock during main ~1.1GHz (R9 counters: VALUBusy x dur
// vs issue count) -> first pass ~20us; 5 structural theories all null.
__global__ __launch_bounds__(BLK, 4) void pdl_main(const float* __restrict__ scan,
                                                   const float* __restrict__ tmpl,
                                                   unsigned* __restrict__ partial,
                                                   float* __restrict__ out,
                                                   int N, int M) {
    const int tid = threadIdx.x;
    const int wave = tid >> 6, lane = tid & 63;
    const bool hi = (lane >= 32);
    const int tsplit = blockIdx.x;                 // 0..53: which 128 template cols
    const int sgroup = blockIdx.y;                 // 0..39
    const int ssplit = sgroup * WPB + wave;        // 0..159: which 10 scan frags

    if (tsplit == 0 && sgroup == 0 && tid == 0) out[0] = 0.0f;

    __shared__ unsigned lmin[TB * 32];
    if (tid < TB * 32) lmin[tid] = KEY_MAX;

    union U { uint4 u; short8 s; };

    // ---- Cold prologue: issue ALL loads (scan + tmpl) before any pack math.
    const int nbase = ssplit * (SA * 32) + (lane & 31);
    float cx[SA], cy[SA], cz[SA];
#pragma unroll
    for (int f = 0; f < SA; ++f) {
        int n = nbase + f * 32; if (n > N - 1) n = N - 1;  // clamp: dup row, min-idempotent
        cx[f] = scan[3 * n + 0];
        cy[f] = scan[3 * n + 1];
        cz[f] = scan[3 * n + 2];
    }
    const int cbase = tsplit * (TB * 32) + (lane & 31);
    float tx[TB], ty[TB], tz[TB];
#pragma unroll
    for (int j = 0; j < TB; ++j) {
        int c = cbase + j * 32;
        if (c > M - 1) c = M - 1;  // clamped dup col; final ignores m>=M
        tx[j] = tmpl[3 * c + 0];
        ty[j] = tmpl[3 * c + 1];
        tz[j] = tmpl[3 * c + 2];
    }

    // A-frag pattern (identical products to R3-R9; -2 folded in):
    //   lanes 0-31 (lo):  {P(-2x), P(-2x), P(-2y), P(-2y)}
    //   lanes 32-63 (hi): {P(-2z), P(-2z), ONE2,   P(s2) }
    unsigned aw01[SA], aw23[SA];
#pragma unroll
    for (int f = 0; f < SA; ++f) {
        const float s2 = fmaf(cx[f], cx[f], fmaf(cy[f], cy[f], cz[f] * cz[f]));
        const float c0 = -2.0f * (hi ? cz[f] : cx[f]);
        const float c1 = hi ? s2 : (-2.0f * cy[f]);
        aw01[f] = packsplit(c0);
        aw23[f] = packsplit(c1);
    }

    // Template B-frag word pattern (identical to R3-R9):
    //   lanes 0-31 (lo):  {xh|xh, xl|xl, yh|yh, yl|yl}
    //   lanes 32-63 (hi): {zh|zh, zl|zl, wh|wl, ONE2}   (w = t2, packed h|l)
    U B[TB];
#pragma unroll
    for (int j = 0; j < TB; ++j) {
        const float t2 = fmaf(tx[j], tx[j], fmaf(ty[j], ty[j], tz[j] * tz[j]));
        const float a0 = hi ? tz[j] : tx[j];
        const float a1 = hi ? t2 : ty[j];
        const unsigned short h0 = f2bf(a0);
        const unsigned short l0 = f2bf(a0 - bf2f(h0));
        const unsigned short h1 = f2bf(a1);
        const unsigned short l1 = f2bf(a1 - bf2f(h1));
        B[j].u.x = (unsigned)h0 | ((unsigned)h0 << 16);
        B[j].u.y = (unsigned)l0 | ((unsigned)l0 << 16);
        B[j].u.z = hi ? ((unsigned)h1 | ((unsigned)l1 << 16))
                      : ((unsigned)h1 | ((unsigned)h1 << 16));
        B[j].u.w = hi ? ONE2
                      : ((unsigned)l1 | ((unsigned)l1 << 16));
    }

    float mn[TB];
#pragma unroll
    for (int j = 0; j < TB; ++j) mn[j] = 3e30f;

    floatx16 zacc;
#pragma unroll
    for (int r = 0; r < 16; ++r) zacc[r] = 0.0f;

    // ---- Inner loop: pure VALU + MFMA. Fully unrolled; statically indexed
    // (rule #20: no scratch). Two d-tiles in flight per pair.
#pragma unroll
    for (int f = 0; f < SA; ++f) {
        U a;
        a.u.x = aw01[f];
        a.u.y = aw01[f];
        a.u.z = hi ? ONE2 : aw23[f];
        a.u.w = aw23[f];
        {
            const floatx16 d0 =
                __builtin_amdgcn_mfma_f32_32x32x16_bf16(a.s, B[0].s, zacc, 0, 0, 0);
            const floatx16 d1 =
                __builtin_amdgcn_mfma_f32_32x32x16_bf16(a.s, B[1].s, zacc, 0, 0, 0);
            mn[0] = dtile_min(d0, mn[0]);
            mn[1] = dtile_min(d1, mn[1]);
        }
        {
            const floatx16 d0 =
                __builtin_amdgcn_mfma_f32_32x32x16_bf16(a.s, B[2].s, zacc, 0, 0, 0);
            const floatx16 d1 =
                __builtin_amdgcn_mfma_f32_32x32x16_bf16(a.s, B[3].s, zacc, 0, 0, 0);
            mn[2] = dtile_min(d0, mn[2]);
            mn[3] = dtile_min(d1, mn[3]);
        }
    }

    __syncthreads();  // lmin init complete before any atomics

    // Merge complementary row-halves (lane ^ 32 holds the other 16 scan rows
    // of the same template column), then block-level LDS merge.
#pragma unroll
    for (int j = 0; j < TB; ++j) {
        const float o = __shfl_xor(mn[j], 32, 64);
        const float v = fminf(mn[j], o);
        if (lane < 32) atomicMin(&lmin[j * 32 + lane], f2key(v));
    }
    __syncthreads();

    // Private (non-atomic) partial slot: no init needed on poisoned ws.
    const size_t base = (size_t)sgroup * COLS + (size_t)tsplit * (TB * 32);
    if (tid < TB * 32) partial[base + tid] = lmin[tid];
}

// Min over the 40 sgroup partials per column, unmap, threshold, reduce, add.
__global__ __launch_bounds__(BLK) void pdl_final(const unsigned* __restrict__ partial,
                                                 float* __restrict__ out, int M) {
    const int m = blockIdx.x * BLK + threadIdx.x;
    float s = 0.0f;
    if (m < M) {
        unsigned k = KEY_MAX;
#pragma unroll 8
        for (int g = 0; g < SGROUPS; ++g)
            k = min(k, partial[(size_t)g * COLS + m]);
        const float v = key2f(k);
        if (v < THRESH) s = v;
    }
#pragma unroll
    for (int off = 32; off > 0; off >>= 1) s += __shfl_down(s, off, 64);

    __shared__ float ls[BLK / 64];
    const int lane = threadIdx.x & 63;
    const int w = threadIdx.x >> 6;
    if (lane == 0) ls[w] = s;
    __syncthreads();
    if (threadIdx.x == 0) {
        float t = 0.0f;
#pragma unroll
        for (int i = 0; i < BLK / 64; ++i) t += ls[i];
        atomicAdd(out, t);
    }
}

extern "C" void kernel_launch(void* const* d_in, const int* in_sizes, int n_in,
                              void* d_out, int out_size, void* d_ws, size_t ws_size,
                              hipStream_t stream) {
    const float* scan = (const float*)d_in[0];   // [N,3] fp32
    const float* tmpl = (const float*)d_in[1];   // [M,3] fp32
    float* out = (float*)d_out;                  // scalar fp32

    const int N = in_sizes[0] / 3;               // 50000
    const int M = in_sizes[1] / 3;               // 6890

    // ws: partial[SGROUPS][COLS] (~1.1 MB), written fully each run (no init).
    unsigned* partial = (unsigned*)d_ws;

    dim3 grid(TSPLITS, SGROUPS);                 // (54, 40) = 2160 blocks
    pdl_main<<<grid, BLK, 0, stream>>>(scan, tmpl, partial, out, N, M);

    pdl_final<<<(M + BLK - 1) / BLK, BLK, 0, stream>>>(partial, out, M);
}